// Round 3
// baseline (280.474 us; speedup 1.0000x reference)
//
#include <hip/hip_runtime.h>

// B=1048576, A=3, N=8, NUM_CLASSES=3, LAMBDA_COORD=5
#define B_SIZE  1048576
#define NBLK    1024           // 1024 blocks x 4 waves = 4096 persistent waves
#define NWAVE   4096
#define TILES   4              // each wave: 4 tiles of 64 batches (4096*4*64 = B)
#define TSTRIDE (NWAVE * 64)   // batches between a wave's consecutive tiles

__device__ __forceinline__ float frcp(float x) { return __builtin_amdgcn_rcpf(x); }

// One register tile: 64 batches/wave, one batch/lane, loaded with per-lane
// float4s (pred row = 96 B, gt row = 128 B, cls row = 32 B; all 16B-aligned).
// No LDS anywhere: R0-R2 proved occupancy/TLP is NOT the limiter; the limiter
// is the full vmcnt drain between each wave's load burst and its math. Ping-pong
// register tiles let tile t+1's loads fly under tile t's math (counted waits).
struct Tile {
    float4 p[6];   // pred row: 24 floats
    float4 g[8];   // gt row:   32 floats
    int4   c0, c1; // classes:  8 ints
};

__device__ __forceinline__ void tile_load(const float* __restrict__ pred,
                                          const float* __restrict__ gt_boxes,
                                          const int*   __restrict__ gt_classes,
                                          int batch, Tile& t) {
    const float4* pp = reinterpret_cast<const float4*>(pred       + (size_t)batch * 24);
    const float4* gp = reinterpret_cast<const float4*>(gt_boxes   + (size_t)batch * 32);
    const int4*   cp = reinterpret_cast<const int4*>(  gt_classes + (size_t)batch * 8);
    #pragma unroll
    for (int k = 0; k < 6; ++k) t.p[k] = pp[k];
    #pragma unroll
    for (int k = 0; k < 8; ++k) t.g[k] = gp[k];
    t.c0 = cp[0]; t.c1 = cp[1];
}

// R2-validated per-batch loss math, unchanged numerics.
__device__ __forceinline__ float tile_math(const Tile& t) {
    float pr[24], gb[32];
    #pragma unroll
    for (int k = 0; k < 6; ++k) {
        pr[k*4+0] = t.p[k].x; pr[k*4+1] = t.p[k].y;
        pr[k*4+2] = t.p[k].z; pr[k*4+3] = t.p[k].w;
    }
    #pragma unroll
    for (int k = 0; k < 8; ++k) {
        gb[k*4+0] = t.g[k].x; gb[k*4+1] = t.g[k].y;
        gb[k*4+2] = t.g[k].z; gb[k*4+3] = t.g[k].w;
    }
    const int gc[8] = {t.c0.x, t.c0.y, t.c0.z, t.c0.w,
                       t.c1.x, t.c1.y, t.c1.z, t.c1.w};

    float total = 0.0f;
    #pragma unroll
    for (int a = 0; a < 3; ++a) {
        const float* p = pr + a * 8;
        const float px = frcp(1.0f + __expf(-p[0]));
        const float py = frcp(1.0f + __expf(-p[1]));
        const float pw = p[2];
        const float ph = p[3];
        const float z  = p[4];
        const float px1 = px - pw * 0.5f, px2 = px + pw * 0.5f;
        const float py1 = py - ph * 0.5f, py2 = py + ph * 0.5f;
        const float pa_eps = (px2 - px1) * (py2 - py1) + 1e-6f;

        float best_iou = -3.4e38f;
        int best_idx = 0;
        #pragma unroll
        for (int n = 0; n < 8; ++n) {
            const float gx = gb[n*4+0], gy = gb[n*4+1];
            const float gw = gb[n*4+2], gh = gb[n*4+3];
            const float hw = gw * 0.5f, hh = gh * 0.5f;
            const float iw = fmaxf(fminf(px2, gx + hw) - fmaxf(px1, gx - hw), 0.0f);
            const float ih = fmaxf(fminf(py2, gy + hh) - fmaxf(py1, gy - hh), 0.0f);
            const float inter = iw * ih;
            const float iou = inter * frcp((pa_eps + gw * gh) - inter);
            const bool upd = iou > best_iou;       // strict > == first-max (argmax)
            best_iou = upd ? iou : best_iou;
            best_idx = upd ? n : best_idx;
        }
        const bool matched = best_iou > 0.5f;

        float mbx = gb[0], mby = gb[1], mbw = gb[2], mbh = gb[3];
        int mcls = gc[0];
        #pragma unroll
        for (int n = 1; n < 8; ++n) {
            const bool s = (best_idx == n);
            mbx = s ? gb[n*4+0] : mbx;
            mby = s ? gb[n*4+1] : mby;
            mbw = s ? gb[n*4+2] : mbw;
            mbh = s ? gb[n*4+3] : mbh;
            mcls = s ? gc[n] : mcls;
        }

        // conf loss via shared softplus (clamped):
        const float az = fabsf(z);
        const float c  = __logf(1.0f + __expf(-az));
        const float sp_pos = fmaxf(z, 0.0f) + c;
        const float sp_neg = fmaxf(-z, 0.0f) + c;
        total += fminf(matched ? sp_neg : sp_pos, 100.0f);

        if (matched) {
            const float dx = px - mbx, dy = py - mby;
            const float dw = pw - mbw, dh = ph - mbh;
            total += 5.0f * (dx*dx + dy*dy + dw*dw + dh*dh);
            const float l0 = p[5], l1 = p[6], l2 = p[7];
            const float m = fmaxf(l0, fmaxf(l1, l2));
            const float lse = m + __logf(__expf(l0-m) + __expf(l1-m) + __expf(l2-m));
            const float sel = (mcls == 0) ? l0 : ((mcls == 1) ? l1 : l2);
            total += lse - sel;
        }
    }
    return total;
}

__device__ __forceinline__ float wave_reduce(float v) {
    #pragma unroll
    for (int off = 32; off > 0; off >>= 1)
        v += __shfl_down(v, off, 64);
    return v;
}

__global__ __launch_bounds__(256) void yolo_loss_kernel(
    const float* __restrict__ pred,       // [B,3,8]  row = 24 floats
    const float* __restrict__ gt_boxes,   // [B,8,4]  row = 32 floats
    const int*   __restrict__ gt_classes, // [B,8]    row = 8 ints
    double* __restrict__ part) {          // [NWAVE] per-wave partials (no atomics)
    const int tid  = threadIdx.x;
    const int wave = tid >> 6;
    const int lane = tid & 63;
    const int wid  = blockIdx.x * 4 + wave;   // 0..4095
    const int base = wid * 64 + lane;         // this lane's tile-0 batch

    Tile ta, tb;
    tile_load(pred, gt_boxes, gt_classes, base + 0 * TSTRIDE, ta);
    tile_load(pred, gt_boxes, gt_classes, base + 1 * TSTRIDE, tb);  // in flight under t0 math

    double dacc = 0.0;
    float  tot;

    // t0: math(ta); prefetch t2 into ta's slot (flies under t1's math)
    tot = tile_math(ta);
    tile_load(pred, gt_boxes, gt_classes, base + 2 * TSTRIDE, ta);
    dacc += (double)wave_reduce(tot);

    // t1: math(tb); prefetch t3 (flies under t2's math)
    tot = tile_math(tb);
    tile_load(pred, gt_boxes, gt_classes, base + 3 * TSTRIDE, tb);
    dacc += (double)wave_reduce(tot);

    // t2, t3: drain
    dacc += (double)wave_reduce(tile_math(ta));
    dacc += (double)wave_reduce(tile_math(tb));

    if (lane == 0)
        part[wid] = dacc;
}

__global__ __launch_bounds__(256) void yolo_reduce_kernel(
    const double* __restrict__ part, float* __restrict__ out) {
    double s = 0.0;
    #pragma unroll
    for (int k = 0; k < NWAVE / 256; ++k)
        s += part[threadIdx.x + k * 256];      // coalesced
    #pragma unroll
    for (int off = 32; off > 0; off >>= 1)
        s += __shfl_down(s, off, 64);
    __shared__ double r[4];
    const int lane = threadIdx.x & 63;
    const int wave = threadIdx.x >> 6;
    if (lane == 0) r[wave] = s;
    __syncthreads();
    if (threadIdx.x == 0)
        out[0] = (float)((r[0] + r[1] + r[2] + r[3]) / (double)B_SIZE);
}

extern "C" void kernel_launch(void* const* d_in, const int* in_sizes, int n_in,
                              void* d_out, int out_size, void* d_ws, size_t ws_size,
                              hipStream_t stream) {
    const float* pred       = (const float*)d_in[0];
    const float* gt_boxes   = (const float*)d_in[1];
    const int*   gt_classes = (const int*)d_in[2];
    float* out   = (float*)d_out;
    double* part = (double*)d_ws;   // 4096 doubles = 32 KB scratch; every slot
                                    // written each launch (poison-safe)

    yolo_loss_kernel<<<NBLK, 256, 0, stream>>>(pred, gt_boxes, gt_classes, part);
    yolo_reduce_kernel<<<1, 256, 0, stream>>>(part, out);
}